// Round 13
// baseline (204.112 us; speedup 1.0000x reference)
//
#include <hip/hip_runtime.h>

typedef float f32x4 __attribute__((ext_vector_type(4)));

#define EPSV 1e-5f

__device__ __forceinline__ float sigmoidf_(float z) {
    return 1.0f / (1.0f + __expf(-z));
}

// ---------------------------------------------------------------------------
// Dispatch 1: stats only — PURE READ of x (103 MB), no tensor output.
// One block per (b,g) group, 1024 threads (16 waves):
//   waves 0-7 : x0 half. wave w owns channels 4w..4w+3 (16 lanes/channel);
//               16-lane shfl reduce -> mean -> pre-sigmoided a0 gate -> ws.
//   waves 8-15: x1 half. wave owns 784 contiguous f4; 64-lane shfl reduce;
//               8-slot LDS combine -> mu/rstd -> per-channel affine (A,B).
// ws layout per bg (96 floats): [0..31]=a0, [32+2c]=A_c, [33+2c]=B_c.
// ---------------------------------------------------------------------------
__global__ __launch_bounds__(1024, 2) void stats_all(
    const f32x4* __restrict__ x4,
    const float* __restrict__ cweight,
    const float* __restrict__ cbias,
    const float* __restrict__ sweight,
    const float* __restrict__ sbias,
    float* __restrict__ ws)
{
    const int bg  = blockIdx.x;
    const int tid = threadIdx.x;
    const int w   = tid >> 6;
    const int ln  = tid & 63;
    const f32x4* __restrict__ xg = x4 + (size_t)bg * 12544;

    __shared__ float lds_s[8], lds_ss[8];

    if (w < 8) {
        // ---- x0 half: per-channel means ----
        const int ch  = 4 * w + (ln >> 4);
        const int l16 = ln & 15;
        const f32x4* __restrict__ xc = xg + ch * 196;
        float s = 0.f;
#pragma unroll
        for (int k = 0; k < 12; ++k) {
            f32x4 v = xc[l16 + 16 * k];
            s += (v.x + v.y) + (v.z + v.w);
        }
        if (l16 < 4) {
            f32x4 v = xc[192 + l16];
            s += (v.x + v.y) + (v.z + v.w);
        }
        s += __shfl_xor(s, 1, 64); s += __shfl_xor(s, 2, 64);
        s += __shfl_xor(s, 4, 64); s += __shfl_xor(s, 8, 64);
        if (l16 == 0) {
            ws[(size_t)bg * 96 + ch] =
                sigmoidf_(cweight[ch] * (s * (1.0f / 784.0f)) + cbias[ch]);
        }
    } else {
        // ---- x1 half: group sum/sumsq ----
        const f32x4* __restrict__ xs = xg + 6272 + (w - 8) * 784;
        float s = 0.f, ss = 0.f;
#pragma unroll
        for (int k = 0; k < 12; ++k) {
            f32x4 v = xs[ln + 64 * k];
            s  += (v.x + v.y) + (v.z + v.w);
            ss += (v.x * v.x + v.y * v.y) + (v.z * v.z + v.w * v.w);
        }
        if (ln < 16) {
            f32x4 v = xs[768 + ln];
            s  += (v.x + v.y) + (v.z + v.w);
            ss += (v.x * v.x + v.y * v.y) + (v.z * v.z + v.w * v.w);
        }
#pragma unroll
        for (int m = 32; m >= 1; m >>= 1) {
            s  += __shfl_xor(s,  m, 64);
            ss += __shfl_xor(ss, m, 64);
        }
        if (ln == 0) { lds_s[w - 8] = s; lds_ss[w - 8] = ss; }
    }
    __syncthreads();

    if (tid < 32) {
        float S = 0.f, SS = 0.f;
#pragma unroll
        for (int i = 0; i < 8; ++i) { S += lds_s[i]; SS += lds_ss[i]; }
        constexpr float inv_n = 1.0f / (32.0f * 784.0f);
        const float mu   = S * inv_n;
        const float var  = SS * inv_n - mu * mu;
        const float rstd = rsqrtf(fmaxf(var, 0.f) + EPSV);
        const float A    = sweight[tid] * rstd;
        ws[(size_t)bg * 96 + 32 + 2 * tid] = A;
        ws[(size_t)bg * 96 + 33 + 2 * tid] = sbias[tid] - A * mu;
    }
}

// ---------------------------------------------------------------------------
// Dispatch 2: PURE STREAM apply with paired-group LINEAR writes.
// Block bid -> (b = bid/8, gp = (bid/2)%4, h = bid%2). Each block produces the
// CONTIGUOUS 12544-f4 output window rows [gp*128+64h, gp*128+64h+64):
//   out row r (0..63): even r <- group gp, odd r <- group gp+4,
//   channel (32h + r/2), col p. Input is read L3-hot (read in dispatch 1);
//   gates come from 64 LDS-cached scalars. No reductions, one barrier.
// ---------------------------------------------------------------------------
__global__ __launch_bounds__(1024, 2) void apply_stream(
    const f32x4* __restrict__ x4,
    const float* __restrict__ ws,
    f32x4* __restrict__ out4)
{
    const int bid = (int)blockIdx.x;
    const int b   = bid >> 3;
    const int gp  = (bid >> 1) & 3;
    const int h   = bid & 1;
    const int tid = threadIdx.x;

    __shared__ float gA[64], gB[64];
    if (tid < 64) {
        const size_t src_bg = (size_t)(b * 8 + gp + 4 * (tid & 1));
        if (h == 0) {
            gA[tid] = ws[src_bg * 96 + (tid >> 1)];
        } else {
            gA[tid] = ws[src_bg * 96 + 32 + 2 * (tid >> 1)];
            gB[tid] = ws[src_bg * 96 + 33 + 2 * (tid >> 1)];
        }
    }
    __syncthreads();

    const size_t in_e = (size_t)(b * 8 + gp)     * 12544 + (size_t)h * 6272;
    const size_t in_o = (size_t)(b * 8 + gp + 4) * 12544 + (size_t)h * 6272;
    f32x4* __restrict__ ob =
        out4 + (size_t)b * 100352 + (size_t)(gp * 128 + 64 * h) * 196;

    if (h == 0) {
        // x0 half: pure multiply by cached gate
#pragma unroll
        for (int k = 0; k < 12; ++k) {
            const int idx = tid + 1024 * k;
            const int r   = idx / 196;
            const int p   = idx - r * 196;
            const f32x4 v = x4[((r & 1) ? in_o : in_e) + (r >> 1) * 196 + p];
            ob[idx] = v * gA[r];
        }
        if (tid < 256) {
            const int idx = 12288 + tid;
            const int r   = idx / 196;
            const int p   = idx - r * 196;
            const f32x4 v = x4[((r & 1) ? in_o : in_e) + (r >> 1) * 196 + p];
            ob[idx] = v * gA[r];
        }
    } else {
        // x1 half: affine + sigmoid gate
#pragma unroll
        for (int k = 0; k < 12; ++k) {
            const int idx = tid + 1024 * k;
            const int r   = idx / 196;
            const int p   = idx - r * 196;
            const f32x4 v = x4[((r & 1) ? in_o : in_e) + (r >> 1) * 196 + p];
            const float A = gA[r], Bq = gB[r];
            f32x4 rr;
            rr.x = v.x * sigmoidf_(A * v.x + Bq);
            rr.y = v.y * sigmoidf_(A * v.y + Bq);
            rr.z = v.z * sigmoidf_(A * v.z + Bq);
            rr.w = v.w * sigmoidf_(A * v.w + Bq);
            ob[idx] = rr;
        }
        if (tid < 256) {
            const int idx = 12288 + tid;
            const int r   = idx / 196;
            const int p   = idx - r * 196;
            const f32x4 v = x4[((r & 1) ? in_o : in_e) + (r >> 1) * 196 + p];
            const float A = gA[r], Bq = gB[r];
            f32x4 rr;
            rr.x = v.x * sigmoidf_(A * v.x + Bq);
            rr.y = v.y * sigmoidf_(A * v.y + Bq);
            rr.z = v.z * sigmoidf_(A * v.z + Bq);
            rr.w = v.w * sigmoidf_(A * v.w + Bq);
            ob[idx] = rr;
        }
    }
}

extern "C" void kernel_launch(void* const* d_in, const int* in_sizes, int n_in,
                              void* d_out, int out_size, void* d_ws, size_t ws_size,
                              hipStream_t stream) {
    const float* x  = (const float*)d_in[0];
    const float* cw = (const float*)d_in[1];
    const float* cb = (const float*)d_in[2];
    const float* sw = (const float*)d_in[3];
    const float* sb = (const float*)d_in[4];
    float* out = (float*)d_out;
    float* ws  = (float*)d_ws;

    const int B = in_sizes[0] / (512 * 784);

    stats_all<<<B * 8, 1024, 0, stream>>>(
        (const f32x4*)x, cw, cb, sw, sb, ws);

    apply_stream<<<B * 8, 1024, 0, stream>>>(
        (const f32x4*)x, ws, (f32x4*)out);
}